// Round 11
// baseline (82.187 us; speedup 1.0000x reference)
//
#include <hip/hip_runtime.h>
#include <hip/hip_fp16.h>
#include <stdint.h>

// out[c,b,g] = sum_{s<8} prod_{l<3} x[b, I[c,g,s,l]]
#define Cc 16
#define Gg 8192
#define Ss 8
#define Ll 3
#define Bb 32
#define ZS 4
#define THREADS 512

// --- Kernel A: xh[z][g] = uint4 of 8 f16 (b = 8z..8z+7)  [z-major: LDS staging]
//               xw[g*4+z] = same uint4                    [g-major 64 B rows: TCP]
__global__ __launch_bounds__(256) void build_tables(const float* __restrict__ x,
                                                    uint4* __restrict__ xh,
                                                    uint4* __restrict__ xw) {
    int t = blockIdx.x * 256 + threadIdx.x;        // over ZS*Gg
    int z = t >> 13;
    int g = t & (Gg - 1);
    uint32_t d[4];
    #pragma unroll
    for (int j = 0; j < 4; ++j) {
        __half2 h = __floats2half2_rn(x[(size_t)(8 * z + 2 * j) * Gg + g],
                                      x[(size_t)(8 * z + 2 * j + 1) * Gg + g]);
        d[j] = *(const uint32_t*)&h;
    }
    uint4 o = make_uint4(d[0], d[1], d[2], d[3]);
    xh[t] = o;
    xw[(size_t)g * 4 + z] = o;
}

__device__ __forceinline__ void flat24(const int4 q[6], int idx[24]) {
    #pragma unroll
    for (int k = 0; k < 6; ++k) {
        idx[4 * k + 0] = q[k].x; idx[4 * k + 1] = q[k].y;
        idx[4 * k + 2] = q[k].z; idx[4 * k + 3] = q[k].w;
    }
}

__device__ __forceinline__ void acc_oct(const uint4& a4, const uint4& b4,
                                        const uint4& d4, float acc[8]) {
    const __half2* a = (const __half2*)&a4;
    const __half2* b = (const __half2*)&b4;
    const __half2* d = (const __half2*)&d4;
    #pragma unroll
    for (int j = 0; j < 4; ++j) {
        __half2 p = __hmul2(__hmul2(a[j], b[j]), d[j]);   // v_pk_mul_f16
        float2 pf = __half22float2(p);
        acc[2 * j]     += pf.x;
        acc[2 * j + 1] += pf.y;
    }
}

// --- Kernel B: hybrid. Block (bx, z): stages slice z; DS-side evaluates 512
// (c,g) with g<4096 (8 b's of slice z); TCP-side evaluates 128 (c,g) with
// g>=4096 for ALL 32 b's (4 threads/eval, one dwordx4 sub-row each).
// TCP gathers ride vmcnt, DS gathers ride lgkmcnt -> the two ~17 us walls
// run concurrently if the pipes are independent (the hypothesis under test).
__global__ __launch_bounds__(THREADS) void clause_hybrid(const uint4* __restrict__ xh,
                                                         const uint4* __restrict__ xw,
                                                         const int* __restrict__ I,
                                                         float* __restrict__ out) {
    __shared__ uint4 xl[Gg];                       // 128 KB
    const int tid = threadIdx.x;
    const int bx = blockIdx.x;                     // 0..127
    const int z = blockIdx.y;                      // 0..3

    // Stage slice z: 16 x 16 B per thread, plain loads (R10-validated).
    {
        const uint4* gs = xh + (size_t)z * Gg;
        uint4 t0[8];
        #pragma unroll
        for (int i = 0; i < 8; ++i) t0[i] = gs[tid + i * THREADS];
        #pragma unroll
        for (int i = 0; i < 8; ++i) xl[tid + i * THREADS] = t0[i];
        #pragma unroll
        for (int i = 0; i < 8; ++i) t0[i] = gs[tid + (8 + i) * THREADS];
        #pragma unroll
        for (int i = 0; i < 8; ++i) xl[tid + (8 + i) * THREADS] = t0[i];
    }

    // DS-side (c,g): c = bx>>3, g = (bx&7)*512 + tid  (g in [0,4096))
    const int cd = bx >> 3;
    const int gd = (bx & 7) * 512 + tid;
    const int4* ipd = (const int4*)(I + ((size_t)cd * Gg + gd) * (Ss * Ll));
    int4 qd[6];
    #pragma unroll
    for (int k = 0; k < 6; ++k) qd[k] = ipd[k];

    // TCP-side (c,g): chunk = z*128+bx; 4 threads share one eval.
    const int chunk = z * 128 + bx;                // 0..511, disjoint across grid
    const int ct = chunk >> 5;                     // 0..15
    const int eid = tid >> 2;                      // 0..127
    const int sub = tid & 3;                       // b-oct: b = 8*sub..8*sub+7
    const int gt = 4096 + (chunk & 31) * 128 + eid;
    const int4* ipt = (const int4*)(I + ((size_t)ct * Gg + gt) * (Ss * Ll));
    int4 qt[6];
    #pragma unroll
    for (int k = 0; k < 6; ++k) qt[k] = ipt[k];    // 4-lane broadcast reads

    __syncthreads();   // drains stage + idx (vmcnt0) — so TCP gathers go AFTER

    // Issue all 24 TCP line-gathers (vmcnt queue; stays in flight under DS work).
    int idxt[24];
    flat24(qt, idxt);
    uint4 vt[24];
    #pragma unroll
    for (int k = 0; k < 24; ++k)
        vt[k] = xw[(size_t)idxt[k] * 4 + sub];     // random 64 B row, 16 B chunk

    // DS eval (lgkmcnt): 24 random b128, double-buffered 6 at a time.
    int idxd[24];
    flat24(qd, idxd);
    float accd[8] = {0, 0, 0, 0, 0, 0, 0, 0};
    {
        uint4 vd[2][6];
        #pragma unroll
        for (int m = 0; m < 6; ++m) vd[0][m] = xl[idxd[m]];
        #pragma unroll
        for (int r = 0; r < 4; ++r) {
            if (r < 3) {
                #pragma unroll
                for (int m = 0; m < 6; ++m) vd[(r + 1) & 1][m] = xl[idxd[6 * (r + 1) + m]];
            }
            const uint4* cvd = vd[r & 1];
            acc_oct(cvd[0], cvd[1], cvd[2], accd);
            acc_oct(cvd[3], cvd[4], cvd[5], accd);
        }
    }

    // DS store: b = 8z+j; lanes span 512 consecutive g -> coalesced.
    {
        float* opd = out + ((size_t)(cd * Bb + 8 * z)) * Gg + gd;
        #pragma unroll
        for (int j = 0; j < 8; ++j)
            opd[(size_t)j * Gg] = accd[j];
    }

    // Consume TCP gathers (vmcnt waits happen here, after ~17 us of DS work).
    {
        float acct[8] = {0, 0, 0, 0, 0, 0, 0, 0};
        #pragma unroll
        for (int s = 0; s < Ss; ++s)
            acc_oct(vt[3 * s], vt[3 * s + 1], vt[3 * s + 2], acct);
        float* opt = out + ((size_t)(ct * Bb + 8 * sub)) * Gg + gt;
        #pragma unroll
        for (int j = 0; j < 8; ++j)
            opt[(size_t)j * Gg] = acct[j];
    }
}

// --- Fallback (ws too small): direct global gather; slow but correct.
__global__ __launch_bounds__(256) void clause_kernel_direct(const float* __restrict__ x,
                                                            const int* __restrict__ I,
                                                            float* __restrict__ out) {
    const int tid = threadIdx.x;
    const int b = tid & 31;
    const int j = tid >> 5;
    const int g = blockIdx.x * 8 + j;
    const int c = blockIdx.y;

    const int* Icg = I + (size_t)(c * Gg + g) * (Ss * Ll);
    float sum = 0.f;
    #pragma unroll
    for (int s = 0; s < Ss; ++s) {
        float p0 = x[(size_t)b * Gg + Icg[3 * s + 0]];
        float p1 = x[(size_t)b * Gg + Icg[3 * s + 1]];
        float p2 = x[(size_t)b * Gg + Icg[3 * s + 2]];
        sum += p0 * p1 * p2;
    }
    out[(size_t)(c * Bb + b) * Gg + g] = sum;
}

extern "C" void kernel_launch(void* const* d_in, const int* in_sizes, int n_in,
                              void* d_out, int out_size, void* d_ws, size_t ws_size,
                              hipStream_t stream) {
    const float* x = (const float*)d_in[0];
    const int* I = (const int*)d_in[1];
    float* out = (float*)d_out;

    const size_t tbl_bytes = (size_t)ZS * Gg * sizeof(uint4);  // 512 KB each

    if (ws_size >= 2 * tbl_bytes) {
        uint4* xh = (uint4*)d_ws;
        uint4* xw = (uint4*)((char*)d_ws + tbl_bytes);
        build_tables<<<(ZS * Gg) / 256, 256, 0, stream>>>(x, xh, xw);
        clause_hybrid<<<dim3(128, ZS), THREADS, 0, stream>>>(xh, xw, I, out);
    } else {
        clause_kernel_direct<<<dim3(Gg / 8, Cc), 256, 0, stream>>>(x, I, out);
    }
}